// Round 5
// baseline (3292.496 us; speedup 1.0000x reference)
//
#include <hip/hip_runtime.h>
#include <math.h>

#define NPG 256
#define NB 1024
#define NN (NB * NPG)          // 262144 nodes
#define HID 192
#define HID2 384
#define NE 4194304
#define KTOP 231
#define LNEPS 1e-5f

#define ROWS 64                // rows (nodes) per block
#define KC 4                   // k-chunk
#define NCH (HID / KC)         // 48 chunks

typedef int   vint4  __attribute__((ext_vector_type(4)));
typedef float vfloat4 __attribute__((ext_vector_type(4)));

// ---------------------------------------------------------------------------
// Kernel A: fused logits = Linear(192->384) -> LayerNorm -> ReLU -> Linear(384->1)
// Lane -> 6 cols (col = lane + 64j), wave -> 16 rows, acc[16][6].
// X staged once in LDS (49152 B -> 3 blocks/CU), read as wave-uniform
// ds_read_b128 broadcasts. W1 is NOT staged in LDS: it is L2-resident
// (288 KB/XCD) and streamed straight into registers with a one-chunk
// ping-pong prefetch (coalesced 64-consecutive-dword loads). One barrier
// total; no per-chunk __syncthreads.
// ---------------------------------------------------------------------------
__global__ __launch_bounds__(256, 3) void logits_kernel(
    const float* __restrict__ h, const float* __restrict__ g,
    const float* __restrict__ W1, const float* __restrict__ b1,
    const float* __restrict__ gamma, const float* __restrict__ beta,
    const float* __restrict__ W2, const float* __restrict__ b2,
    float* __restrict__ logits_out)
{
    __shared__ float Xs[ROWS * HID];        // 64*192*4 = 49152 B

    const int tid  = threadIdx.x;
    const int lane = tid & 63;
    const int wav  = tid >> 6;              // 0..3
    const int row0 = blockIdx.x * ROWS;
    const int graph = row0 >> 8;            // row0 / NPG

    // stage X = h + g_rep (64 rows x 192 cols = 3072 float4, 12 per thread)
    {
        const float4* h4 = (const float4*)(h + (size_t)row0 * HID);
        const float4* g4 = (const float4*)(g + (size_t)graph * HID);
        #pragma unroll
        for (int it = 0; it < 12; ++it) {
            int f = tid + it * 256;
            int r = f / 48, c = f - r * 48;        // c in float4 units
            float4 hv = h4[r * 48 + c];
            float4 gv = g4[c];
            *(float4*)(&Xs[r * HID + c * 4]) =
                make_float4(hv.x + gv.x, hv.y + gv.y, hv.z + gv.z, hv.w + gv.w);
        }
    }

    float acc[16][6];
    #pragma unroll
    for (int r = 0; r < 16; ++r)
        #pragma unroll
        for (int j = 0; j < 6; ++j) acc[r][j] = 0.f;

    const float* Wlane = W1 + lane;
    auto loadW = [&](float* dst, int s) {
        const float* wp = Wlane + (size_t)s * (KC * HID2);
        #pragma unroll
        for (int kk = 0; kk < KC; ++kk)
            #pragma unroll
            for (int j = 0; j < 6; ++j)
                dst[kk * 6 + j] = wp[kk * HID2 + j * 64];
    };
    auto compute = [&](const float* w, int s) {
        const float* Xp = &Xs[(wav * 16) * HID + s * KC];
        #pragma unroll
        for (int r = 0; r < 16; ++r) {
            float4 x = *(const float4*)(Xp + r * HID);   // wave-uniform broadcast
            #pragma unroll
            for (int j = 0; j < 6; ++j) {
                acc[r][j] = fmaf(x.x, w[0 * 6 + j], acc[r][j]);
                acc[r][j] = fmaf(x.y, w[1 * 6 + j], acc[r][j]);
                acc[r][j] = fmaf(x.z, w[2 * 6 + j], acc[r][j]);
                acc[r][j] = fmaf(x.w, w[3 * 6 + j], acc[r][j]);
            }
        }
    };

    float wA[24], wB[24];
    loadW(wA, 0);                 // overlaps with X staging stores
    __syncthreads();              // the only barrier

    for (int s = 0; s < NCH; s += 2) {
        loadW(wB, s + 1);
        compute(wA, s);
        if (s + 2 < NCH) loadW(wA, s + 2);
        compute(wB, s + 1);
    }

    // epilogue: +b1, LayerNorm across the wave (64 lanes x 6 cols), ReLU,
    // dot with W2, +b2. Full-wave shfl reductions per row.
    float b1v[6], gav[6], bev[6], w2v[6];
    #pragma unroll
    for (int j = 0; j < 6; ++j) {
        int c = j * 64 + lane;
        b1v[j] = b1[c]; gav[j] = gamma[c]; bev[j] = beta[c]; w2v[j] = W2[c];
    }
    const float b2v = b2[0];

    #pragma unroll
    for (int r = 0; r < 16; ++r) {
        float z[6];
        float s1 = 0.f, s2 = 0.f;
        #pragma unroll
        for (int j = 0; j < 6; ++j) {
            z[j] = acc[r][j] + b1v[j];
            s1 += z[j];
            s2 += z[j] * z[j];
        }
        #pragma unroll
        for (int off = 1; off < 64; off <<= 1) {
            s1 += __shfl_xor(s1, off);
            s2 += __shfl_xor(s2, off);
        }
        float mu  = s1 * (1.f / HID2);
        float var = s2 * (1.f / HID2) - mu * mu;
        float rs  = rsqrtf(var + LNEPS);
        float lg = 0.f;
        #pragma unroll
        for (int j = 0; j < 6; ++j) {
            float zn = (z[j] - mu) * rs * gav[j] + bev[j];
            zn = fmaxf(zn, 0.f);
            lg = fmaf(zn, w2v[j], lg);
        }
        #pragma unroll
        for (int off = 1; off < 64; off <<= 1) lg += __shfl_xor(lg, off);
        if (lane == 0) logits_out[row0 + wav * 16 + r] = lg + b2v;
    }
}

// ---------------------------------------------------------------------------
// Kernel B: per-graph top-K via rank counting (stable, ties by lower index =
// jax.lax.top_k). Emits kl[n] = kept ? logit : NaN. Zeroes touched bytes.
// ---------------------------------------------------------------------------
__global__ __launch_bounds__(256) void topk_kernel(
    const float* __restrict__ logits, float* __restrict__ kl,
    unsigned char* __restrict__ touched)
{
    __shared__ float arr[NPG];
    const int tid = threadIdx.x;
    const int n = blockIdx.x * NPG + tid;
    float v = logits[n];
    arr[tid] = v;
    touched[n] = 0;
    __syncthreads();
    int rank = 0;
    #pragma unroll 16
    for (int j = 0; j < NPG; ++j) {
        float a = arr[j];
        rank += (a > v || (a == v && j < tid)) ? 1 : 0;
    }
    kl[n] = (rank < KTOP) ? v : __builtin_nanf("");
}

// ---------------------------------------------------------------------------
// Kernel C: edge mask + weight + touched marking. NaN-poisoned logits make
// mask = !isnan(ls+ld). Nontemporal hints on the 96 MB edge stream so the
// kl gather table / touched stay L2-resident. (native ext_vector types for
// the nontemporal builtins — HIP_vector_type is rejected)
// ---------------------------------------------------------------------------
__global__ __launch_bounds__(256) void edge_kernel(
    const int* __restrict__ ei, const float* __restrict__ kl,
    vfloat4* __restrict__ mask_out, vfloat4* __restrict__ w_out,
    unsigned char* __restrict__ touched)
{
    const int t = blockIdx.x * blockDim.x + threadIdx.x;   // [0, NE/4)
    const vint4 s4 = __builtin_nontemporal_load(((const vint4*)ei) + t);
    const vint4 d4 = __builtin_nontemporal_load(((const vint4*)(ei + NE)) + t);

    vfloat4 m, w;
    #pragma unroll
    for (int i = 0; i < 4; ++i) {
        float ls = kl[s4[i]];
        float ld = kl[d4[i]];
        float sum = ls + ld;
        bool ok = (sum == sum);          // false if either endpoint dropped
        m[i] = ok ? 1.0f : 0.0f;
        w[i] = ok ? sum : 0.0f;
        if (ok) {
            touched[s4[i]] = 1;
            touched[d4[i]] = 1;
        }
    }
    __builtin_nontemporal_store(m, mask_out + t);
    __builtin_nontemporal_store(w, w_out + t);
}

// ---------------------------------------------------------------------------
// Kernel D: node mask from touched bytes (4 nodes per thread)
// ---------------------------------------------------------------------------
__global__ __launch_bounds__(256) void nodemask_kernel(
    const uchar4* __restrict__ touched, vfloat4* __restrict__ nm)
{
    const int t = blockIdx.x * blockDim.x + threadIdx.x;   // [0, NN/4)
    uchar4 tv = touched[t];
    vfloat4 o;
    o[0] = tv.x ? 1.f : 0.f;
    o[1] = tv.y ? 1.f : 0.f;
    o[2] = tv.z ? 1.f : 0.f;
    o[3] = tv.w ? 1.f : 0.f;
    __builtin_nontemporal_store(o, nm + t);
}

extern "C" void kernel_launch(void* const* d_in, const int* in_sizes, int n_in,
                              void* d_out, int out_size, void* d_ws, size_t ws_size,
                              hipStream_t stream)
{
    const float* h     = (const float*)d_in[0];
    const float* g     = (const float*)d_in[1];
    const int*   ei    = (const int*)d_in[2];
    const float* W1    = (const float*)d_in[3];
    const float* b1    = (const float*)d_in[4];
    const float* gamma = (const float*)d_in[5];
    const float* beta  = (const float*)d_in[6];
    const float* W2    = (const float*)d_in[7];
    const float* b2    = (const float*)d_in[8];

    float* out        = (float*)d_out;
    float* out_mask   = out;                       // [E]
    float* out_w      = out + (size_t)NE;          // [E]
    float* out_logits = out + 2 * (size_t)NE;      // [N]
    float* out_nm     = out_logits + (size_t)NN;   // [N]

    float*         kl      = (float*)d_ws;                                   // N floats
    unsigned char* touched = (unsigned char*)((char*)d_ws + (size_t)NN * 4); // N bytes

    hipLaunchKernelGGL(logits_kernel, dim3(NN / ROWS), dim3(256), 0, stream,
                       h, g, W1, b1, gamma, beta, W2, b2, out_logits);
    hipLaunchKernelGGL(topk_kernel, dim3(NB), dim3(256), 0, stream,
                       out_logits, kl, touched);
    hipLaunchKernelGGL(edge_kernel, dim3(NE / 1024), dim3(256), 0, stream,
                       ei, kl, (vfloat4*)out_mask, (vfloat4*)out_w, touched);
    hipLaunchKernelGGL(nodemask_kernel, dim3(NN / 1024), dim3(256), 0, stream,
                       (const uchar4*)touched, (vfloat4*)out_nm);
}